// Round 1
// baseline (275.291 us; speedup 1.0000x reference)
//
#include <hip/hip_runtime.h>
#include <stdint.h>

#define B 32
#define P 24564
#define NCLS 21
#define NOBJ 24
#define THRESH 0.5f
#define SCHUNK 16
#define CHUNK 1536   // ceil(24564/16)

// ws layout (bytes)
#define OFF_ACC     0        // double[3]: loc_sum, conf_pos, conf_neg
#define OFF_NPOS    32       // int[B]
#define OFF_OBJBEST 160      // ull[B*NOBJ] = 6144 B
#define INIT_BYTES  6304
#define OFF_TRUECLS 6304     // uchar[B*P] = 786048 B
#define OFF_CENEG   792352   // float[B*P] = 3144192 B (16-aligned)

__device__ __forceinline__ unsigned long long umax64(unsigned long long a, unsigned long long b) {
    return a > b ? a : b;
}

// ---------------- Kernel A1: per-object best prior (argmax over p, first-index tie) ----------
__global__ __launch_bounds__(256) void k_objmax(
    const float* __restrict__ gt_boxes, const float* __restrict__ anchor,
    unsigned long long* __restrict__ obj_best) {
#pragma clang fp contract(off)
    int b = blockIdx.y;
    int p0 = blockIdx.x * CHUNK;
    int p1 = min(P, p0 + CHUNK);
    int tid = threadIdx.x;
    __shared__ float4 sbox[NOBJ];
    __shared__ unsigned long long sbest[NOBJ];
    if (tid < NOBJ) {
        const float* g = gt_boxes + (size_t)(b * NOBJ + tid) * 4;
        sbox[tid] = make_float4(g[0], g[1], g[2], g[3]);
        sbest[tid] = 0ull;
    }
    __syncthreads();
    unsigned long long best[NOBJ];
#pragma unroll
    for (int n = 0; n < NOBJ; n++) best[n] = 0ull;

    for (int p = p0 + tid; p < p1; p += 256) {
        const float* a = anchor + (size_t)p * 4;
        float acx = a[0], acy = a[1], aw = a[2], ah = a[3];
        float ax0 = acx - aw * 0.5f, ay0 = acy - ah * 0.5f;
        float ax1 = acx + aw * 0.5f, ay1 = acy + ah * 0.5f;
        float area_a = (ax1 - ax0) * (ay1 - ay0);
        unsigned long long pk = (unsigned long long)(~(unsigned)p);
#pragma unroll
        for (int n = 0; n < NOBJ; n++) {
            float4 bx = sbox[n];
            float ltx = fmaxf(bx.x, ax0), lty = fmaxf(bx.y, ay0);
            float rbx = fminf(bx.z, ax1), rby = fminf(bx.w, ay1);
            float w = fmaxf(rbx - ltx, 0.f), h = fmaxf(rby - lty, 0.f);
            float inter = w * h;
            float area_o = (bx.z - bx.x) * (bx.w - bx.y);
            float iou = inter / (area_o + area_a - inter);
            unsigned long long key = ((unsigned long long)__float_as_uint(iou) << 32) | pk;
            best[n] = umax64(best[n], key);
        }
    }
#pragma unroll
    for (int n = 0; n < NOBJ; n++) {
        unsigned long long v = best[n];
        for (int off = 32; off > 0; off >>= 1)
            v = umax64(v, __shfl_down(v, off, 64));
        if ((tid & 63) == 0) atomicMax(&sbest[n], v);
    }
    __syncthreads();
    if (tid < NOBJ) atomicMax(&obj_best[b * NOBJ + tid], sbest[tid]);
}

// ---------------- Kernel A2: per-prior match, true_cls, loc-L1, n_pos ------------------------
__global__ __launch_bounds__(256) void k_match(
    const float* __restrict__ gt_boxes, const int* __restrict__ gt_labels,
    const float* __restrict__ anchor, const float* __restrict__ pred_loc,
    const unsigned long long* __restrict__ obj_best,
    unsigned char* __restrict__ true_cls, int* __restrict__ n_pos,
    double* __restrict__ acc) {
#pragma clang fp contract(off)
    int b = blockIdx.y;
    int p0 = blockIdx.x * CHUNK;
    int p1 = min(P, p0 + CHUNK);
    int tid = threadIdx.x;
    __shared__ float4 sbox[NOBJ];
    __shared__ int slab[NOBJ];
    __shared__ int sobj[NOBJ];
    __shared__ float swsum[4];
    __shared__ int swnp[4];
    if (tid < NOBJ) {
        const float* g = gt_boxes + (size_t)(b * NOBJ + tid) * 4;
        sbox[tid] = make_float4(g[0], g[1], g[2], g[3]);
        slab[tid] = gt_labels[b * NOBJ + tid];
        sobj[tid] = (int)(~(unsigned)(obj_best[b * NOBJ + tid] & 0xFFFFFFFFull));
    }
    __syncthreads();
    float lsum = 0.f;
    int lnp = 0;
    for (int p = p0 + tid; p < p1; p += 256) {
        const float* a = anchor + (size_t)p * 4;
        float acx = a[0], acy = a[1], aw = a[2], ah = a[3];
        float ax0 = acx - aw * 0.5f, ay0 = acy - ah * 0.5f;
        float ax1 = acx + aw * 0.5f, ay1 = acy + ah * 0.5f;
        float area_a = (ax1 - ax0) * (ay1 - ay0);
        float bv = -1.f;
        int bn = 0;
#pragma unroll
        for (int n = 0; n < NOBJ; n++) {
            float4 bx = sbox[n];
            float ltx = fmaxf(bx.x, ax0), lty = fmaxf(bx.y, ay0);
            float rbx = fminf(bx.z, ax1), rby = fminf(bx.w, ay1);
            float w = fmaxf(rbx - ltx, 0.f), h = fmaxf(rby - lty, 0.f);
            float inter = w * h;
            float area_o = (bx.z - bx.x) * (bx.w - bx.y);
            float iou = inter / (area_o + area_a - inter);
            if (p == sobj[n]) iou = 1.0f;
            if (iou > bv) { bv = iou; bn = n; }
        }
        int pos = (bv >= THRESH) ? 1 : 0;
        true_cls[(size_t)b * P + p] = (unsigned char)(pos ? (slab[bn] + 1) : 0);
        if (pos) {
            lnp++;
            float4 bx = sbox[bn];
            float bcx = (bx.x + bx.z) * 0.5f, bcy = (bx.y + bx.w) * 0.5f;
            float bw = bx.z - bx.x, bh = bx.w - bx.y;
            float t0 = (bcx - acx) / (aw / 10.0f);
            float t1 = (bcy - acy) / (ah / 10.0f);
            float t2 = logf(bw / aw) * 5.0f;
            float t3 = logf(bh / ah) * 5.0f;
            float4 pl = *(const float4*)(pred_loc + (size_t)(b * P + p) * 4);
            lsum += fabsf(pl.x - t0) + fabsf(pl.y - t1) + fabsf(pl.z - t2) + fabsf(pl.w - t3);
        }
    }
    for (int off = 32; off > 0; off >>= 1) {
        lsum += __shfl_down(lsum, off, 64);
        lnp  += __shfl_down(lnp, off, 64);
    }
    if ((tid & 63) == 0) { swsum[tid >> 6] = lsum; swnp[tid >> 6] = lnp; }
    __syncthreads();
    if (tid == 0) {
        float s = swsum[0] + swsum[1] + swsum[2] + swsum[3];
        int np = swnp[0] + swnp[1] + swnp[2] + swnp[3];
        atomicAdd(&n_pos[b], np);
        atomicAdd(&acc[0], (double)s);
    }
}

// ---------------- Kernel B: cross-entropy, conf_pos, ce_neg ----------------------------------
__global__ __launch_bounds__(256) void k_ce(
    const float* __restrict__ pred_cls, const unsigned char* __restrict__ true_cls,
    float* __restrict__ ce_neg, double* __restrict__ acc) {
    __shared__ __align__(16) float sx[256 * NCLS];
    __shared__ float swsum[4];
    int tid = threadIdx.x;
    int blockStart = blockIdx.x * 256;
    int nelem = min(256, B * P - blockStart);
    int nflt = nelem * NCLS;
    const float* gbase = pred_cls + (size_t)blockStart * NCLS;
    int nf4 = nflt >> 2;
    const float4* g4 = (const float4*)gbase;
    for (int i = tid; i < nf4; i += 256) ((float4*)sx)[i] = g4[i];
    for (int i = (nf4 << 2) + tid; i < nflt; i += 256) sx[i] = gbase[i];
    __syncthreads();
    float cp = 0.f;
    if (tid < nelem) {
        int idx = blockStart + tid;
        const float* x = sx + tid * NCLS;
        float m = x[0];
#pragma unroll
        for (int j = 1; j < NCLS; j++) m = fmaxf(m, x[j]);
        float s = 0.f;
#pragma unroll
        for (int j = 0; j < NCLS; j++) s += expf(x[j] - m);
        int c = true_cls[idx];
        float ce = m + logf(s) - x[c];
        if (c > 0) { cp = ce; ce_neg[idx] = 0.f; }
        else       { ce_neg[idx] = ce; }
    }
    for (int off = 32; off > 0; off >>= 1) cp += __shfl_down(cp, off, 64);
    if ((tid & 63) == 0) swsum[tid >> 6] = cp;
    __syncthreads();
    if (tid == 0) atomicAdd(&acc[1], (double)(swsum[0] + swsum[1] + swsum[2] + swsum[3]));
}

// ---------------- Kernel C: per-batch top-K sum via bitwise binary search --------------------
__global__ __launch_bounds__(256) void k_topk(
    const float* __restrict__ ce_neg, const int* __restrict__ n_pos,
    double* __restrict__ acc) {
    int b = blockIdx.x;
    int tid = threadIdx.x;
    __shared__ int scnt[4];
    __shared__ double ssum[4];
    const uint4* x4 = (const uint4*)(ce_neg + (size_t)b * P);
    const int n4 = P / 4;  // 6141
    int K = n_pos[b] * 3;
    if (K > P) K = P;
    if (K <= 0) return;

    unsigned T = 0;
    for (int bit = 30; bit >= 0; bit--) {
        unsigned cand = T | (1u << bit);
        int cnt = 0;
        for (int i = tid; i < n4; i += 256) {
            uint4 v = x4[i];
            cnt += (v.x >= cand) + (v.y >= cand) + (v.z >= cand) + (v.w >= cand);
        }
        for (int off = 32; off > 0; off >>= 1) cnt += __shfl_down(cnt, off, 64);
        if ((tid & 63) == 0) scnt[tid >> 6] = cnt;
        __syncthreads();
        int total = scnt[0] + scnt[1] + scnt[2] + scnt[3];
        __syncthreads();
        if (total >= K) T = cand;
    }
    // sum of elements strictly greater than T, plus (K - cnt_gt) copies of T
    int cgt = 0;
    double s = 0.0;
    for (int i = tid; i < n4; i += 256) {
        uint4 v = x4[i];
        if (v.x > T) { cgt++; s += (double)__uint_as_float(v.x); }
        if (v.y > T) { cgt++; s += (double)__uint_as_float(v.y); }
        if (v.z > T) { cgt++; s += (double)__uint_as_float(v.z); }
        if (v.w > T) { cgt++; s += (double)__uint_as_float(v.w); }
    }
    for (int off = 32; off > 0; off >>= 1) {
        cgt += __shfl_down(cgt, off, 64);
        s   += __shfl_down(s, off, 64);
    }
    if ((tid & 63) == 0) { scnt[tid >> 6] = cgt; ssum[tid >> 6] = s; }
    __syncthreads();
    if (tid == 0) {
        int cg = scnt[0] + scnt[1] + scnt[2] + scnt[3];
        double sum = ssum[0] + ssum[1] + ssum[2] + ssum[3];
        sum += (double)(K - cg) * (double)__uint_as_float(T);
        atomicAdd(&acc[2], sum);
    }
}

// ---------------- Kernel D: final scalars -----------------------------------------------------
__global__ void k_final(const int* __restrict__ n_pos, const double* __restrict__ acc,
                        float* __restrict__ out) {
    if (threadIdx.x == 0) {
        int npt = 0;
        for (int b = 0; b < B; b++) npt += n_pos[b];
        double npf = (double)npt;
        float conf = (float)((acc[1] + acc[2]) / npf);
        float loc  = 10.0f * (float)(acc[0] / (npf * 4.0));
        out[0] = conf + loc;
        out[1] = conf;
        out[2] = loc;
    }
}

extern "C" void kernel_launch(void* const* d_in, const int* in_sizes, int n_in,
                              void* d_out, int out_size, void* d_ws, size_t ws_size,
                              hipStream_t stream) {
    const float* pred_cls = (const float*)d_in[0];
    const float* pred_loc = (const float*)d_in[1];
    const float* gt_boxes = (const float*)d_in[2];
    const int*   gt_labels = (const int*)d_in[3];
    const float* anchor   = (const float*)d_in[4];
    float* out = (float*)d_out;
    char* ws = (char*)d_ws;
    double* acc = (double*)(ws + OFF_ACC);
    int* n_pos = (int*)(ws + OFF_NPOS);
    unsigned long long* obj_best = (unsigned long long*)(ws + OFF_OBJBEST);
    unsigned char* true_cls = (unsigned char*)(ws + OFF_TRUECLS);
    float* ce_neg = (float*)(ws + OFF_CENEG);

    hipMemsetAsync(ws, 0, INIT_BYTES, stream);
    k_objmax<<<dim3(SCHUNK, B), 256, 0, stream>>>(gt_boxes, anchor, obj_best);
    k_match<<<dim3(SCHUNK, B), 256, 0, stream>>>(gt_boxes, gt_labels, anchor, pred_loc,
                                                 obj_best, true_cls, n_pos, acc);
    k_ce<<<(B * P + 255) / 256, 256, 0, stream>>>(pred_cls, true_cls, ce_neg, acc);
    k_topk<<<B, 256, 0, stream>>>(ce_neg, n_pos, acc);
    k_final<<<1, 64, 0, stream>>>(n_pos, acc, out);
}